// Round 2
// baseline (312.223 us; speedup 1.0000x reference)
//
#include <hip/hip_runtime.h>

// Problem constants (fixed by the reference)
#define NGRAPH 16
#define NPG    4096
#define KCL    64
#define DF     128
#define NTOT   (NGRAPH*NPG)     // 65536
#define NEDGE  (NTOT*16)        // 1048576

// output layout (floats)
//   out       [0, 131072)
//   out_adj   [131072, 196608)
//   link_loss 196608
//   entropy   196609
//   batch     [196610, 197634)
//   batch_ptr [197634, 197651)

// ws layout (bytes)
//   clus   uint8[65536]      @ 0
//   counts int[1024]         @ 65536
//   cross  float[16]         @ 69632
//   asq    float[16]         @ 69696

// ---------------------------------------------------------------------------
// Kernel 1: per-node argmax assignment (logits GEMM + gumbel), writes clus.
// No atomics at all.
// ---------------------------------------------------------------------------
__global__ __launch_bounds__(256) void assign_kernel(
    const float* __restrict__ x, const float* __restrict__ W,
    const float* __restrict__ bias, const float* __restrict__ gum,
    unsigned char* __restrict__ clus)
{
    __shared__ __align__(16) float xs[64 * 132];   // 64 nodes x 128, pad 132
    __shared__ float cand_v[4][64];
    __shared__ int   cand_k[4][64];

    const int tid  = threadIdx.x;
    const int wave = tid >> 6;
    const int lane = tid & 63;
    const int n0   = blockIdx.x * 64;     // first node of this block

    // ---- stage x tile: 64 rows x 128 floats, coalesced float4 ----
    {
        const float4* xg = (const float4*)(x + (size_t)n0 * DF);
        #pragma unroll
        for (int i = 0; i < 8; ++i) {
            int j4 = tid + i * 256;     // float4 index within tile
            int j  = j4 << 2;
            float4 v = xg[j4];
            *(float4*)&xs[(j >> 7) * 132 + (j & 127)] = v;
        }
    }
    __syncthreads();

    // ---- logits for 16 k's per wave, lane = node ----
    const int n  = lane;
    const int k0 = __builtin_amdgcn_readfirstlane(wave << 4);  // wave-uniform

    float acc[16];
    #pragma unroll
    for (int kk = 0; kk < 16; ++kk) acc[kk] = bias[k0 + kk];

    #pragma unroll 4
    for (int dc = 0; dc < 32; ++dc) {
        float4 xv = *(const float4*)&xs[n * 132 + (dc << 2)];
        const float* wp = W + (dc << 8) + k0;    // W[(4*dc)*64 + k0]
        #pragma unroll
        for (int kk = 0; kk < 16; ++kk) {
            float a = acc[kk];
            a = fmaf(xv.x, wp[kk],        a);
            a = fmaf(xv.y, wp[64  + kk],  a);
            a = fmaf(xv.z, wp[128 + kk],  a);
            a = fmaf(xv.w, wp[192 + kk],  a);
            acc[kk] = a;
        }
    }

    // ---- gumbel noise + per-wave argmax (first-max tie-break, k ascending) ----
    const float* gp = gum + ((size_t)(n0 + n) << 6) + k0;
    float best = -3.4e38f; int bestk = k0;
    #pragma unroll
    for (int q = 0; q < 4; ++q) {
        float4 u = *(const float4*)(gp + (q << 2));
        float uv[4] = {u.x, u.y, u.z, u.w};
        #pragma unroll
        for (int r = 0; r < 4; ++r) {
            float g = -logf(-logf(uv[r]));
            float v = acc[(q << 2) + r] + g;
            if (v > best) { best = v; bestk = k0 + (q << 2) + r; }
        }
    }
    cand_v[wave][n] = best;
    cand_k[wave][n] = bestk;
    __syncthreads();

    // ---- combine across the 4 waves (k-chunk ascending => global first-max) ----
    if (tid < 64) {
        float bv = cand_v[0][tid]; int bk = cand_k[0][tid];
        #pragma unroll
        for (int w2 = 1; w2 < 4; ++w2) {
            float v = cand_v[w2][tid];
            if (v > bv) { bv = v; bk = cand_k[w2][tid]; }
        }
        clus[n0 + tid] = (unsigned char)bk;
    }
}

// ---------------------------------------------------------------------------
// Kernel 2: pooled features out[bg*64+c, :] += x[n, :] — LDS-aggregated per
// quarter-graph (1024 nodes), flushed with 4-contender global atomics.
// Also produces cluster counts.
// ---------------------------------------------------------------------------
__global__ __launch_bounds__(512) void pool_kernel(
    const float* __restrict__ x, const unsigned char* __restrict__ clus,
    int* __restrict__ counts, float* __restrict__ out)
{
    __shared__ float acc[KCL * DF];        // 32 KB
    __shared__ int   cnt[KCL];
    __shared__ unsigned char cl[1024];

    const int tid  = threadIdx.x;
    const int wave = tid >> 6;             // 0..7
    const int lane = tid & 63;
    const int bg   = blockIdx.x >> 2;      // graph id
    const int q    = blockIdx.x & 3;       // quarter

    #pragma unroll
    for (int i = 0; i < 16; ++i) acc[tid + i * 512] = 0.0f;
    if (tid < KCL) cnt[tid] = 0;
    if (tid < 256) ((int*)cl)[tid] = ((const int*)(clus + (size_t)bg * 4096 + q * 1024))[tid];
    __syncthreads();

    const int nb = bg * 4096 + q * 1024;   // first node (global id)

    // wave handles one node per iteration; lanes cover dims via float2
    #pragma unroll 4
    for (int it = 0; it < 128; ++it) {
        const int nl = (it << 3) + wave;         // local node id 0..1023
        const int c  = cl[nl];
        const float2 v = ((const float2*)(x + (size_t)(nb + nl) * DF))[lane];
        atomicAdd(&acc[(c << 7) + (lane << 1)],     v.x);
        atomicAdd(&acc[(c << 7) + (lane << 1) + 1], v.y);
        if (lane == 0) atomicAdd(&cnt[c], 1);
    }
    __syncthreads();

    // flush: 8192 floats, 4 contending blocks per cell
    #pragma unroll
    for (int i = 0; i < 16; ++i) {
        const int j = tid + i * 512;
        atomicAdd(&out[(size_t)bg * 8192 + j], acc[j]);
    }
    if (tid < KCL) atomicAdd(&counts[(bg << 6) + tid], cnt[tid]);
}

// ---------------------------------------------------------------------------
// Kernel 3: edge aggregation — LDS 64x64 adj tile per quarter-graph
// (16384 edges), LDS-resident cluster table, 4-contender flush.
// ---------------------------------------------------------------------------
__global__ __launch_bounds__(512) void edge_kernel(
    const int* __restrict__ ei, const float* __restrict__ ew,
    const unsigned char* __restrict__ clus,
    float* __restrict__ out_adj, float* __restrict__ cross,
    float* __restrict__ asq)
{
    __shared__ float adj[KCL * KCL];       // 16 KB
    __shared__ unsigned char cl[4096];     // whole graph's clusters
    __shared__ float redc[8], redq[8];

    const int tid = threadIdx.x;
    const int bg  = blockIdx.x >> 2;
    const int q   = blockIdx.x & 3;

    #pragma unroll
    for (int i = 0; i < 8; ++i) adj[tid + i * 512] = 0.0f;
    #pragma unroll
    for (int i = 0; i < 2; ++i)
        ((int*)cl)[tid + i * 512] = ((const int*)(clus + (size_t)bg * 4096))[tid + i * 512];
    __syncthreads();

    const int e0 = bg * 65536 + q * 16384;
    float csum = 0.0f, qsum = 0.0f;

    #pragma unroll 4
    for (int it = 0; it < 32; ++it) {
        const int e = e0 + it * 512 + tid;
        const int s = ei[e]         & (NPG - 1);   // local node (graphs 4096-aligned)
        const int d = ei[NEDGE + e] & (NPG - 1);
        const float w = ew[e];
        const int ks = cl[s];
        const int kd = cl[d];
        atomicAdd(&adj[(ks << 6) + kd], w);
        csum += (ks == kd) ? w : 0.0f;
        qsum += w * w;
    }

    // block reduction for cross / asq
    #pragma unroll
    for (int off = 32; off > 0; off >>= 1) {
        csum += __shfl_down(csum, off);
        qsum += __shfl_down(qsum, off);
    }
    const int lane = tid & 63, wv = tid >> 6;
    if (lane == 0) { redc[wv] = csum; redq[wv] = qsum; }
    __syncthreads();
    if (tid == 0) {
        float cs = 0.0f, qs = 0.0f;
        #pragma unroll
        for (int i = 0; i < 8; ++i) { cs += redc[i]; qs += redq[i]; }
        atomicAdd(&cross[bg], cs);
        atomicAdd(&asq[bg],  qs);
    }

    // flush adj tile: 4096 floats, 4 contending blocks per cell
    #pragma unroll
    for (int i = 0; i < 8; ++i) {
        const int j = tid + i * 512;
        atomicAdd(&out_adj[(bg << 12) + j], adj[j]);
    }
}

// ---------------------------------------------------------------------------
// Kernel 4: losses + constant outputs
// ---------------------------------------------------------------------------
__global__ __launch_bounds__(1024) void finalize_kernel(
    const int* __restrict__ counts, const float* __restrict__ cross,
    const float* __restrict__ asq, float* __restrict__ out)
{
    __shared__ float links[16];
    const int tid = threadIdx.x;
    const int wv = tid >> 6, lane = tid & 63;   // wave wv handles graph wv

    float c  = (float)counts[(wv << 6) + lane];
    float s2 = c * c;
    #pragma unroll
    for (int off = 32; off > 0; off >>= 1) s2 += __shfl_down(s2, off);
    if (lane == 0) {
        float v = asq[wv] - 2.0f * cross[wv] + s2;
        links[wv] = sqrtf(fmaxf(v, 0.0f)) * (1.0f / 65536.0f);
    }
    __syncthreads();
    if (tid == 0) {
        float m = 0.0f;
        #pragma unroll
        for (int i = 0; i < 16; ++i) m += links[i];
        out[196608] = m * (1.0f / 16.0f);   // link_loss
        out[196609] = 0.0f;                 // entropy_loss (exactly 0 for one-hot)
    }
    // batch = repeat(arange(16), 64)
    out[196610 + tid] = (float)(tid >> 6);
    // batch_ptr_out = arange(17) * 64
    if (tid < 17) out[197634 + tid] = (float)(tid * 64);
}

extern "C" void kernel_launch(void* const* d_in, const int* in_sizes, int n_in,
                              void* d_out, int out_size, void* d_ws, size_t ws_size,
                              hipStream_t stream) {
    const float* x    = (const float*)d_in[0];
    const float* W    = (const float*)d_in[1];
    const float* bias = (const float*)d_in[2];
    const float* ew   = (const float*)d_in[3];
    const float* gum  = (const float*)d_in[4];
    const int*   ei   = (const int*)  d_in[5];
    // d_in[6] = batch_ptr (int64) — unused, graphs are equal-sized

    float* out = (float*)d_out;

    unsigned char* clus  = (unsigned char*)d_ws;
    int*   counts = (int*)  ((char*)d_ws + 65536);
    float* cross  = (float*)((char*)d_ws + 69632);
    float* asq    = (float*)((char*)d_ws + 69696);

    // zero the accumulated regions (harness poisons d_out/d_ws with 0xAA)
    hipMemsetAsync(d_out, 0, (size_t)196608 * sizeof(float), stream);   // out + out_adj
    hipMemsetAsync((char*)d_ws + 65536, 0, 4096 + 128, stream);         // counts + cross + asq

    assign_kernel<<<NTOT / 64, 256, 0, stream>>>(x, W, bias, gum, clus);

    pool_kernel<<<NGRAPH * 4, 512, 0, stream>>>(x, clus, counts, out);

    edge_kernel<<<NGRAPH * 4, 512, 0, stream>>>(
        ei, ew, clus, out + 131072, cross, asq);

    finalize_kernel<<<1, 1024, 0, stream>>>(counts, cross, asq, out);
}

// Round 3
// 156.465 us; speedup vs baseline: 1.9955x; 1.9955x over previous
//
#include <hip/hip_runtime.h>

// Problem constants (fixed by the reference)
#define NGRAPH 16
#define NPG    4096
#define KCL    64
#define DF     128
#define NTOT   (NGRAPH*NPG)     // 65536
#define NEDGE  (NTOT*16)        // 1048576

// output layout (floats)
//   out       [0, 131072)
//   out_adj   [131072, 196608)
//   link_loss 196608
//   entropy   196609
//   batch     [196610, 197634)
//   batch_ptr [197634, 197651)

// ws layout (bytes)
//   clus   uint8[65536]   @ 0
//   counts int[1024]      @ 65536
//   starts int[1024]      @ 69632
//   cross  float[16]      @ 73728
//   asq    float[16]      @ 73792
//   order  uint16[65536]  @ 73856   (node ids sorted by cluster, per graph)

// ---------------------------------------------------------------------------
// Kernel 1: per-node argmax assignment (logits GEMM + gumbel), writes clus.
// ---------------------------------------------------------------------------
__global__ __launch_bounds__(256) void assign_kernel(
    const float* __restrict__ x, const float* __restrict__ W,
    const float* __restrict__ bias, const float* __restrict__ gum,
    unsigned char* __restrict__ clus)
{
    __shared__ __align__(16) float xs[64 * 132];   // 64 nodes x 128, pad 132
    __shared__ float cand_v[4][64];
    __shared__ int   cand_k[4][64];

    const int tid  = threadIdx.x;
    const int wave = tid >> 6;
    const int lane = tid & 63;
    const int n0   = blockIdx.x * 64;     // first node of this block

    // ---- stage x tile: 64 rows x 128 floats, coalesced float4 ----
    {
        const float4* xg = (const float4*)(x + (size_t)n0 * DF);
        #pragma unroll
        for (int i = 0; i < 8; ++i) {
            int j4 = tid + i * 256;     // float4 index within tile
            int j  = j4 << 2;
            float4 v = xg[j4];
            *(float4*)&xs[(j >> 7) * 132 + (j & 127)] = v;
        }
    }
    __syncthreads();

    // ---- logits for 16 k's per wave, lane = node ----
    const int n  = lane;
    const int k0 = __builtin_amdgcn_readfirstlane(wave << 4);  // wave-uniform

    float acc[16];
    #pragma unroll
    for (int kk = 0; kk < 16; ++kk) acc[kk] = bias[k0 + kk];

    #pragma unroll 4
    for (int dc = 0; dc < 32; ++dc) {
        float4 xv = *(const float4*)&xs[n * 132 + (dc << 2)];
        const float* wp = W + (dc << 8) + k0;    // W[(4*dc)*64 + k0]
        #pragma unroll
        for (int kk = 0; kk < 16; ++kk) {
            float a = acc[kk];
            a = fmaf(xv.x, wp[kk],        a);
            a = fmaf(xv.y, wp[64  + kk],  a);
            a = fmaf(xv.z, wp[128 + kk],  a);
            a = fmaf(xv.w, wp[192 + kk],  a);
            acc[kk] = a;
        }
    }

    // ---- gumbel noise + per-wave argmax (first-max tie-break, k ascending) ----
    const float* gp = gum + ((size_t)(n0 + n) << 6) + k0;
    float best = -3.4e38f; int bestk = k0;
    #pragma unroll
    for (int q = 0; q < 4; ++q) {
        float4 u = *(const float4*)(gp + (q << 2));
        float uv[4] = {u.x, u.y, u.z, u.w};
        #pragma unroll
        for (int r = 0; r < 4; ++r) {
            float g = -__logf(-__logf(uv[r]));
            float v = acc[(q << 2) + r] + g;
            if (v > best) { best = v; bestk = k0 + (q << 2) + r; }
        }
    }
    cand_v[wave][n] = best;
    cand_k[wave][n] = bestk;
    __syncthreads();

    // ---- combine across the 4 waves (k-chunk ascending => global first-max) ----
    if (tid < 64) {
        float bv = cand_v[0][tid]; int bk = cand_k[0][tid];
        #pragma unroll
        for (int w2 = 1; w2 < 4; ++w2) {
            float v = cand_v[w2][tid];
            if (v > bv) { bv = v; bk = cand_k[w2][tid]; }
        }
        clus[n0 + tid] = (unsigned char)bk;
    }
}

// ---------------------------------------------------------------------------
// Kernel 2: counting sort per graph — histogram (=counts), prefix (=starts),
// scatter node ids into cluster-sorted order[].
// ---------------------------------------------------------------------------
__global__ __launch_bounds__(1024) void sort_kernel(
    const unsigned char* __restrict__ clus,
    int* __restrict__ counts, int* __restrict__ starts,
    unsigned short* __restrict__ order)
{
    __shared__ int hist[KCL];
    __shared__ int offs[KCL];

    const int tid = threadIdx.x;
    const int bg  = blockIdx.x;

    if (tid < KCL) hist[tid] = 0;
    __syncthreads();

    unsigned char c[4];
    #pragma unroll
    for (int i = 0; i < 4; ++i) {
        c[i] = clus[(bg << 12) + tid + (i << 10)];
        atomicAdd(&hist[c[i]], 1);
    }
    __syncthreads();

    if (tid < KCL) {
        int v = hist[tid];              // inclusive scan across wave 0 (64-wide)
        int inc = v;
        #pragma unroll
        for (int off = 1; off < 64; off <<= 1) {
            int t = __shfl_up(inc, off);
            if (tid >= off) inc += t;
        }
        int excl = inc - v;
        offs[tid] = excl;
        counts[(bg << 6) + tid] = v;
        starts[(bg << 6) + tid] = excl;
    }
    __syncthreads();

    #pragma unroll
    for (int i = 0; i < 4; ++i) {
        int p = atomicAdd(&offs[c[i]], 1);
        order[(bg << 12) + p] = (unsigned short)(tid + (i << 10));
    }
}

// ---------------------------------------------------------------------------
// Kernel 3: segment-sum pooling. One block per (graph, cluster); plain
// stores, zero atomics. Also covers zero-count clusters (writes zeros).
// ---------------------------------------------------------------------------
__global__ __launch_bounds__(256) void pool_kernel(
    const float* __restrict__ x, const unsigned short* __restrict__ order,
    const int* __restrict__ counts, const int* __restrict__ starts,
    float* __restrict__ out)
{
    __shared__ unsigned short ord[NPG];       // worst case: whole graph
    __shared__ float4 part[8][32];

    const int tid   = threadIdx.x;
    const int bg    = blockIdx.x >> 6;
    const int k     = blockIdx.x & 63;
    const int cnt   = counts[(bg << 6) + k];
    const int start = starts[(bg << 6) + k];

    for (int i = tid; i < cnt; i += 256)
        ord[i] = order[(bg << 12) + start + i];
    __syncthreads();

    const int grp = tid >> 5;    // 0..7 (row group)
    const int l32 = tid & 31;    // float4 lane within row
    float4 acc = {0.0f, 0.0f, 0.0f, 0.0f};
    for (int i = grp; i < cnt; i += 8) {
        const float4* row = (const float4*)(x + ((size_t)(bg << 12) + ord[i]) * DF);
        float4 v = row[l32];
        acc.x += v.x; acc.y += v.y; acc.z += v.z; acc.w += v.w;
    }
    part[grp][l32] = acc;
    __syncthreads();

    if (grp == 0) {
        float4 s = part[0][l32];
        #pragma unroll
        for (int g = 1; g < 8; ++g) {
            float4 p = part[g][l32];
            s.x += p.x; s.y += p.y; s.z += p.z; s.w += p.w;
        }
        ((float4*)(out + (size_t)(bg << 13) + (k << 7)))[l32] = s;
    }
}

// ---------------------------------------------------------------------------
// Kernel 4: edge aggregation — LDS 64x64 adj tile per quarter-graph
// (16384 edges), LDS-resident cluster table, 4-contender flush.
// ---------------------------------------------------------------------------
__global__ __launch_bounds__(512) void edge_kernel(
    const int* __restrict__ ei, const float* __restrict__ ew,
    const unsigned char* __restrict__ clus,
    float* __restrict__ out_adj, float* __restrict__ cross,
    float* __restrict__ asq)
{
    __shared__ float adj[KCL * KCL];       // 16 KB
    __shared__ unsigned char cl[NPG];      // whole graph's clusters
    __shared__ float redc[8], redq[8];

    const int tid = threadIdx.x;
    const int bg  = blockIdx.x >> 2;
    const int q   = blockIdx.x & 3;

    #pragma unroll
    for (int i = 0; i < 8; ++i) adj[tid + i * 512] = 0.0f;
    #pragma unroll
    for (int i = 0; i < 2; ++i)
        ((int*)cl)[tid + i * 512] = ((const int*)(clus + (size_t)bg * NPG))[tid + i * 512];
    __syncthreads();

    const int e0 = bg * 65536 + q * 16384;
    float csum = 0.0f, qsum = 0.0f;

    #pragma unroll 4
    for (int it = 0; it < 32; ++it) {
        const int e = e0 + it * 512 + tid;
        const int s = ei[e]         & (NPG - 1);   // local node (graphs 4096-aligned)
        const int d = ei[NEDGE + e] & (NPG - 1);
        const float w = ew[e];
        const int ks = cl[s];
        const int kd = cl[d];
        atomicAdd(&adj[(ks << 6) + kd], w);
        csum += (ks == kd) ? w : 0.0f;
        qsum += w * w;
    }

    #pragma unroll
    for (int off = 32; off > 0; off >>= 1) {
        csum += __shfl_down(csum, off);
        qsum += __shfl_down(qsum, off);
    }
    const int lane = tid & 63, wv = tid >> 6;
    if (lane == 0) { redc[wv] = csum; redq[wv] = qsum; }
    __syncthreads();
    if (tid == 0) {
        float cs = 0.0f, qs = 0.0f;
        #pragma unroll
        for (int i = 0; i < 8; ++i) { cs += redc[i]; qs += redq[i]; }
        atomicAdd(&cross[bg], cs);
        atomicAdd(&asq[bg],  qs);
    }

    // flush adj tile: 4096 floats, 4 contending blocks per cell
    #pragma unroll
    for (int i = 0; i < 8; ++i) {
        const int j = tid + i * 512;
        atomicAdd(&out_adj[(bg << 12) + j], adj[j]);
    }
}

// ---------------------------------------------------------------------------
// Kernel 5: losses + constant outputs
// ---------------------------------------------------------------------------
__global__ __launch_bounds__(1024) void finalize_kernel(
    const int* __restrict__ counts, const float* __restrict__ cross,
    const float* __restrict__ asq, float* __restrict__ out)
{
    __shared__ float links[16];
    const int tid = threadIdx.x;
    const int wv = tid >> 6, lane = tid & 63;   // wave wv handles graph wv

    float c  = (float)counts[(wv << 6) + lane];
    float s2 = c * c;
    #pragma unroll
    for (int off = 32; off > 0; off >>= 1) s2 += __shfl_down(s2, off);
    if (lane == 0) {
        float v = asq[wv] - 2.0f * cross[wv] + s2;
        links[wv] = sqrtf(fmaxf(v, 0.0f)) * (1.0f / 65536.0f);
    }
    __syncthreads();
    if (tid == 0) {
        float m = 0.0f;
        #pragma unroll
        for (int i = 0; i < 16; ++i) m += links[i];
        out[196608] = m * (1.0f / 16.0f);   // link_loss
        out[196609] = 0.0f;                 // entropy_loss (exactly 0 for one-hot)
    }
    // batch = repeat(arange(16), 64)
    out[196610 + tid] = (float)(tid >> 6);
    // batch_ptr_out = arange(17) * 64
    if (tid < 17) out[197634 + tid] = (float)(tid * 64);
}

extern "C" void kernel_launch(void* const* d_in, const int* in_sizes, int n_in,
                              void* d_out, int out_size, void* d_ws, size_t ws_size,
                              hipStream_t stream) {
    const float* x    = (const float*)d_in[0];
    const float* W    = (const float*)d_in[1];
    const float* bias = (const float*)d_in[2];
    const float* ew   = (const float*)d_in[3];
    const float* gum  = (const float*)d_in[4];
    const int*   ei   = (const int*)  d_in[5];
    // d_in[6] = batch_ptr (int64) — unused, graphs are equal-sized

    float* out = (float*)d_out;

    unsigned char*  clus   = (unsigned char*) d_ws;
    int*            counts = (int*)           ((char*)d_ws + 65536);
    int*            starts = (int*)           ((char*)d_ws + 69632);
    float*          cross  = (float*)         ((char*)d_ws + 73728);
    float*          asq    = (float*)         ((char*)d_ws + 73792);
    unsigned short* order  = (unsigned short*)((char*)d_ws + 73856);

    // zero only the atomically-accumulated regions:
    //   out_adj (out[131072..196608)) and cross/asq
    hipMemsetAsync(out + 131072, 0, (size_t)65536 * sizeof(float), stream);
    hipMemsetAsync((char*)d_ws + 73728, 0, 128, stream);

    assign_kernel<<<NTOT / 64, 256, 0, stream>>>(x, W, bias, gum, clus);

    sort_kernel<<<NGRAPH, 1024, 0, stream>>>(clus, counts, starts, order);

    pool_kernel<<<NGRAPH * KCL, 256, 0, stream>>>(x, order, counts, starts, out);

    edge_kernel<<<NGRAPH * 4, 512, 0, stream>>>(
        ei, ew, clus, out + 131072, cross, asq);

    finalize_kernel<<<1, 1024, 0, stream>>>(counts, cross, asq, out);
}

// Round 4
// 136.184 us; speedup vs baseline: 2.2927x; 1.1489x over previous
//
#include <hip/hip_runtime.h>

// Problem constants (fixed by the reference)
#define NGRAPH 16
#define NPG    4096
#define KCL    64
#define DF     128
#define NTOT   (NGRAPH*NPG)     // 65536
#define NEDGE  (NTOT*16)        // 1048576

// output layout (floats)
//   out       [0, 131072)
//   out_adj   [131072, 196608)
//   link_loss 196608
//   entropy   196609
//   batch     [196610, 197634)
//   batch_ptr [197634, 197651)

// ws layout (bytes) — everything plain-stored, nothing needs zeroing
//   clus     uint8[65536]      @ 0
//   counts   int[1024]         @ 65536
//   starts   int[1024]         @ 69632
//   crossp   float[256]        @ 73728   (per-edge-block partials)
//   asqp     float[256]        @ 74752
//   order    uint16[65536]     @ 75776
//   partials float[256][4096]  @ 206848  (per-edge-block 64x64 adj tiles)

// ---------------------------------------------------------------------------
// Kernel 1: per-node argmax assignment (logits GEMM + gumbel), writes clus.
// ---------------------------------------------------------------------------
__global__ __launch_bounds__(256) void assign_kernel(
    const float* __restrict__ x, const float* __restrict__ W,
    const float* __restrict__ bias, const float* __restrict__ gum,
    unsigned char* __restrict__ clus)
{
    __shared__ __align__(16) float xs[64 * 132];   // 64 nodes x 128, pad 132
    __shared__ float cand_v[4][64];
    __shared__ int   cand_k[4][64];

    const int tid  = threadIdx.x;
    const int wave = tid >> 6;
    const int lane = tid & 63;
    const int n0   = blockIdx.x * 64;     // first node of this block

    // ---- stage x tile: 64 rows x 128 floats, coalesced float4 ----
    {
        const float4* xg = (const float4*)(x + (size_t)n0 * DF);
        #pragma unroll
        for (int i = 0; i < 8; ++i) {
            int j4 = tid + i * 256;     // float4 index within tile
            int j  = j4 << 2;
            float4 v = xg[j4];
            *(float4*)&xs[(j >> 7) * 132 + (j & 127)] = v;
        }
    }
    __syncthreads();

    // ---- logits for 16 k's per wave, lane = node ----
    const int n  = lane;
    const int k0 = __builtin_amdgcn_readfirstlane(wave << 4);  // wave-uniform

    float acc[16];
    #pragma unroll
    for (int kk = 0; kk < 16; ++kk) acc[kk] = bias[k0 + kk];

    #pragma unroll 4
    for (int dc = 0; dc < 32; ++dc) {
        float4 xv = *(const float4*)&xs[n * 132 + (dc << 2)];
        const float* wp = W + (dc << 8) + k0;    // W[(4*dc)*64 + k0]
        #pragma unroll
        for (int kk = 0; kk < 16; ++kk) {
            float a = acc[kk];
            a = fmaf(xv.x, wp[kk],        a);
            a = fmaf(xv.y, wp[64  + kk],  a);
            a = fmaf(xv.z, wp[128 + kk],  a);
            a = fmaf(xv.w, wp[192 + kk],  a);
            acc[kk] = a;
        }
    }

    // ---- gumbel noise + per-wave argmax (first-max tie-break, k ascending) ----
    const float* gp = gum + ((size_t)(n0 + n) << 6) + k0;
    float best = -3.4e38f; int bestk = k0;
    #pragma unroll
    for (int q = 0; q < 4; ++q) {
        float4 u = *(const float4*)(gp + (q << 2));
        float uv[4] = {u.x, u.y, u.z, u.w};
        #pragma unroll
        for (int r = 0; r < 4; ++r) {
            float g = -__logf(-__logf(uv[r]));
            float v = acc[(q << 2) + r] + g;
            if (v > best) { best = v; bestk = k0 + (q << 2) + r; }
        }
    }
    cand_v[wave][n] = best;
    cand_k[wave][n] = bestk;
    __syncthreads();

    // ---- combine across the 4 waves (k-chunk ascending => global first-max) ----
    if (tid < 64) {
        float bv = cand_v[0][tid]; int bk = cand_k[0][tid];
        #pragma unroll
        for (int w2 = 1; w2 < 4; ++w2) {
            float v = cand_v[w2][tid];
            if (v > bv) { bv = v; bk = cand_k[w2][tid]; }
        }
        clus[n0 + tid] = (unsigned char)bk;
    }
}

// ---------------------------------------------------------------------------
// Kernel 2: counting sort per graph — histogram (=counts), prefix (=starts),
// scatter node ids into cluster-sorted order[].
// ---------------------------------------------------------------------------
__global__ __launch_bounds__(1024) void sort_kernel(
    const unsigned char* __restrict__ clus,
    int* __restrict__ counts, int* __restrict__ starts,
    unsigned short* __restrict__ order)
{
    __shared__ int hist[KCL];
    __shared__ int offs[KCL];

    const int tid = threadIdx.x;
    const int bg  = blockIdx.x;

    if (tid < KCL) hist[tid] = 0;
    __syncthreads();

    unsigned char c[4];
    #pragma unroll
    for (int i = 0; i < 4; ++i) {
        c[i] = clus[(bg << 12) + tid + (i << 10)];
        atomicAdd(&hist[c[i]], 1);
    }
    __syncthreads();

    if (tid < KCL) {
        int v = hist[tid];              // inclusive scan across wave 0 (64-wide)
        int inc = v;
        #pragma unroll
        for (int off = 1; off < 64; off <<= 1) {
            int t = __shfl_up(inc, off);
            if (tid >= off) inc += t;
        }
        int excl = inc - v;
        offs[tid] = excl;
        counts[(bg << 6) + tid] = v;
        starts[(bg << 6) + tid] = excl;
    }
    __syncthreads();

    #pragma unroll
    for (int i = 0; i < 4; ++i) {
        int p = atomicAdd(&offs[c[i]], 1);
        order[(bg << 12) + p] = (unsigned short)(tid + (i << 10));
    }
}

// ---------------------------------------------------------------------------
// Kernel 3: segment-sum pooling. One block per (graph, cluster); plain
// stores, zero atomics. Also covers zero-count clusters (writes zeros).
// ---------------------------------------------------------------------------
__global__ __launch_bounds__(256) void pool_kernel(
    const float* __restrict__ x, const unsigned short* __restrict__ order,
    const int* __restrict__ counts, const int* __restrict__ starts,
    float* __restrict__ out)
{
    __shared__ unsigned short ord[NPG];       // worst case: whole graph
    __shared__ float4 part[8][32];

    const int tid   = threadIdx.x;
    const int bg    = blockIdx.x >> 6;
    const int k     = blockIdx.x & 63;
    const int cnt   = counts[(bg << 6) + k];
    const int start = starts[(bg << 6) + k];

    for (int i = tid; i < cnt; i += 256)
        ord[i] = order[(bg << 12) + start + i];
    __syncthreads();

    const int grp = tid >> 5;    // 0..7 (row group)
    const int l32 = tid & 31;    // float4 lane within row
    float4 acc = {0.0f, 0.0f, 0.0f, 0.0f};
    for (int i = grp; i < cnt; i += 8) {
        const float4* row = (const float4*)(x + ((size_t)(bg << 12) + ord[i]) * DF);
        float4 v = row[l32];
        acc.x += v.x; acc.y += v.y; acc.z += v.z; acc.w += v.w;
    }
    part[grp][l32] = acc;
    __syncthreads();

    if (grp == 0) {
        float4 s = part[0][l32];
        #pragma unroll
        for (int g = 1; g < 8; ++g) {
            float4 p = part[g][l32];
            s.x += p.x; s.y += p.y; s.z += p.z; s.w += p.w;
        }
        ((float4*)(out + (size_t)(bg << 13) + (k << 7)))[l32] = s;
    }
}

// ---------------------------------------------------------------------------
// Kernel 4: edge aggregation — 16 slices per graph (4096 edges each), LDS
// 64x64 adj tile, plain-store per-block partials (no global atomics).
// ---------------------------------------------------------------------------
__global__ __launch_bounds__(512) void edge_kernel(
    const int* __restrict__ ei, const float* __restrict__ ew,
    const unsigned char* __restrict__ clus,
    float* __restrict__ partials, float* __restrict__ crossp,
    float* __restrict__ asqp)
{
    __shared__ float adj[KCL * KCL];       // 16 KB
    __shared__ unsigned char cl[NPG];      // whole graph's clusters
    __shared__ float redc[8], redq[8];

    const int tid = threadIdx.x;
    const int bg  = blockIdx.x >> 4;       // graph
    const int sl  = blockIdx.x & 15;       // slice

    #pragma unroll
    for (int i = 0; i < 8; ++i) adj[tid + i * 512] = 0.0f;
    #pragma unroll
    for (int i = 0; i < 2; ++i)
        ((int*)cl)[tid + i * 512] = ((const int*)(clus + (size_t)bg * NPG))[tid + i * 512];
    __syncthreads();

    const int e0 = bg * 65536 + sl * 4096;
    float csum = 0.0f, qsum = 0.0f;

    #pragma unroll
    for (int it = 0; it < 8; ++it) {
        const int e = e0 + it * 512 + tid;
        const int s = ei[e]         & (NPG - 1);   // local node (graphs 4096-aligned)
        const int d = ei[NEDGE + e] & (NPG - 1);
        const float w = ew[e];
        const int ks = cl[s];
        const int kd = cl[d];
        atomicAdd(&adj[(ks << 6) + kd], w);
        csum += (ks == kd) ? w : 0.0f;
        qsum += w * w;
    }

    #pragma unroll
    for (int off = 32; off > 0; off >>= 1) {
        csum += __shfl_down(csum, off);
        qsum += __shfl_down(qsum, off);
    }
    const int lane = tid & 63, wv = tid >> 6;
    if (lane == 0) { redc[wv] = csum; redq[wv] = qsum; }
    __syncthreads();   // also guarantees all LDS atomics into adj are done

    if (tid == 0) {
        float cs = 0.0f, qs = 0.0f;
        #pragma unroll
        for (int i = 0; i < 8; ++i) { cs += redc[i]; qs += redq[i]; }
        crossp[blockIdx.x] = cs;
        asqp[blockIdx.x]   = qs;
    }

    // flush adj tile: plain float4 stores to this block's private partial
    float4*       dst = (float4*)(partials + (size_t)blockIdx.x * 4096);
    const float4* src = (const float4*)adj;
    dst[tid]       = src[tid];
    dst[tid + 512] = src[tid + 512];
}

// ---------------------------------------------------------------------------
// Kernel 5: reduce slice-partials -> out_adj (blocks 0..63), losses +
// constants (block 64).
// ---------------------------------------------------------------------------
__global__ __launch_bounds__(1024) void reduce_finalize_kernel(
    const float* __restrict__ partials, const float* __restrict__ crossp,
    const float* __restrict__ asqp, const int* __restrict__ counts,
    float* __restrict__ out)
{
    const int tid = threadIdx.x;

    if (blockIdx.x < 64) {
        const int cell = blockIdx.x * 1024 + tid;   // 0..65535
        const int bg   = cell >> 12;
        const int j    = cell & 4095;
        float s = 0.0f;
        #pragma unroll
        for (int sl = 0; sl < 16; ++sl)
            s += partials[(size_t)((bg << 4) + sl) * 4096 + j];
        out[131072 + cell] = s;
        return;
    }

    // block 64: losses + constant outputs
    __shared__ float links[16];
    const int wv = tid >> 6, lane = tid & 63;   // wave wv handles graph wv

    float c  = (float)counts[(wv << 6) + lane];
    float s2 = c * c;
    #pragma unroll
    for (int off = 32; off > 0; off >>= 1) s2 += __shfl_down(s2, off);

    float cp = (lane < 16) ? crossp[(wv << 4) + lane] : 0.0f;
    float ap = (lane < 16) ? asqp[(wv << 4) + lane]   : 0.0f;
    #pragma unroll
    for (int off = 8; off > 0; off >>= 1) {
        cp += __shfl_down(cp, off);
        ap += __shfl_down(ap, off);
    }
    if (lane == 0) {
        float v = ap - 2.0f * cp + s2;
        links[wv] = sqrtf(fmaxf(v, 0.0f)) * (1.0f / 65536.0f);
    }
    __syncthreads();
    if (tid == 0) {
        float m = 0.0f;
        #pragma unroll
        for (int i = 0; i < 16; ++i) m += links[i];
        out[196608] = m * (1.0f / 16.0f);   // link_loss
        out[196609] = 0.0f;                 // entropy_loss (exactly 0 for one-hot)
    }
    // batch = repeat(arange(16), 64)
    out[196610 + tid] = (float)(tid >> 6);
    // batch_ptr_out = arange(17) * 64
    if (tid < 17) out[197634 + tid] = (float)(tid * 64);
}

extern "C" void kernel_launch(void* const* d_in, const int* in_sizes, int n_in,
                              void* d_out, int out_size, void* d_ws, size_t ws_size,
                              hipStream_t stream) {
    const float* x    = (const float*)d_in[0];
    const float* W    = (const float*)d_in[1];
    const float* bias = (const float*)d_in[2];
    const float* ew   = (const float*)d_in[3];
    const float* gum  = (const float*)d_in[4];
    const int*   ei   = (const int*)  d_in[5];
    // d_in[6] = batch_ptr (int64) — unused, graphs are equal-sized

    float* out = (float*)d_out;

    unsigned char*  clus     = (unsigned char*) d_ws;
    int*            counts   = (int*)           ((char*)d_ws + 65536);
    int*            starts   = (int*)           ((char*)d_ws + 69632);
    float*          crossp   = (float*)         ((char*)d_ws + 73728);
    float*          asqp     = (float*)         ((char*)d_ws + 74752);
    unsigned short* order    = (unsigned short*)((char*)d_ws + 75776);
    float*          partials = (float*)         ((char*)d_ws + 206848);

    // no memsets: every output/ws word we consume is plain-stored first

    assign_kernel<<<NTOT / 64, 256, 0, stream>>>(x, W, bias, gum, clus);

    sort_kernel<<<NGRAPH, 1024, 0, stream>>>(clus, counts, starts, order);

    pool_kernel<<<NGRAPH * KCL, 256, 0, stream>>>(x, order, counts, starts, out);

    edge_kernel<<<NGRAPH * 16, 512, 0, stream>>>(
        ei, ew, clus, partials, crossp, asqp);

    reduce_finalize_kernel<<<65, 1024, 0, stream>>>(
        partials, crossp, asqp, counts, out);
}